// Round 1
// baseline (364.184 us; speedup 1.0000x reference)
//
#include <hip/hip_runtime.h>

// Problem constants (from reference)
#define N_IN   256
#define N_REG  256
#define NBATCH 4096
#define TT     64
#define TC     32              // time-chunk staged in LDS
#define NCHUNK (TT / TC)
#define TILE_LD 257            // +1 pad: breaks power-of-2 stride on staging writes

// One block per batch element. Thread tid owns register tid.
// LDS: tile[TC][257] = 32.9 KB (sigmoid'd inputs for one time chunk)
//      st0/st1       =  2.0 KB (double-buffered states -> 1 barrier/step)
__global__ __launch_bounds__(256, 4) void circuit_scan(
    const float* __restrict__ P,
    const int*   __restrict__ wa,
    const int*   __restrict__ wb,
    float*       __restrict__ out)
{
    __shared__ float tile[TC][TILE_LD];
    __shared__ float st0[N_REG];
    __shared__ float st1[N_REG];

    const int tid = threadIdx.x;
    const int b   = blockIdx.x;

    // Indices are constant across steps/batches: load once.
    const int  ia   = wa[tid];
    const int  ib   = wb[tid];
    const bool a_in = ia < N_IN;
    const bool b_in = ib < N_IN;
    const int  ia_m = a_in ? ia : (ia - N_IN);
    const int  ib_m = b_in ? ib : (ib - N_IN);

    st0[tid] = 0.5f;          // initial states, buffer 0

    // Staging lane mapping: 8 iterations x (32 rows x 8 float4-slots).
    // Each float4 covers 4 consecutive t; 8 consecutive lanes cover a
    // 128-B contiguous segment of one input row -> decent coalescing.
    const int row = tid >> 3;   // 0..31
    const int q   = tid & 7;    // 0..7

    float4 regs[8];

    // Prefetch chunk 0
    #pragma unroll
    for (int it = 0; it < 8; ++it) {
        const int r = it * 32 + row;
        regs[it] = *reinterpret_cast<const float4*>(
            P + (size_t)r * (NBATCH * TT) + (size_t)b * TT + q * 4);
    }

    float mystate = 0.5f;

    for (int c = 0; c < NCHUNK; ++c) {
        // sigmoid(4*clip(p,-2,2)) and write tile[t][r]
        #pragma unroll
        for (int it = 0; it < 8; ++it) {
            const int r = it * 32 + row;
            float xv[4] = {regs[it].x, regs[it].y, regs[it].z, regs[it].w};
            #pragma unroll
            for (int j = 0; j < 4; ++j) {
                float x = xv[j];
                x = fminf(2.0f, fmaxf(-2.0f, x));
                float s = 1.0f / (1.0f + __expf(-4.0f * x));
                tile[q * 4 + j][r] = s;
            }
        }
        // Issue next chunk's loads now; they stay in flight across the scan.
        if (c + 1 < NCHUNK) {
            const int t0 = (c + 1) * TC;
            #pragma unroll
            for (int it = 0; it < 8; ++it) {
                const int r = it * 32 + row;
                regs[it] = *reinterpret_cast<const float4*>(
                    P + (size_t)r * (NBATCH * TT) + (size_t)b * TT + t0 + q * 4);
            }
        }
        __syncthreads();   // tile + states visible

        // 32 scan steps, one barrier each (state double-buffer)
        #pragma unroll
        for (int tl = 0; tl < TC; ++tl) {
            const float* sread  = (tl & 1) ? st1 : st0;
            float*       swrite = (tl & 1) ? st0 : st1;
            const float* arow   = &tile[tl][0];
            float a  = *(a_in ? (arow + ia_m) : (sread + ia_m));
            float bb = *(b_in ? (arow + ib_m) : (sread + ib_m));
            float ns = a + bb - 2.0f * a * bb;
            swrite[tid] = ns;
            mystate = ns;
            __syncthreads();
        }
        // Last step's barrier also protects tile from next chunk's overwrite.
    }

    out[(size_t)b * N_REG + tid] = mystate;
}

extern "C" void kernel_launch(void* const* d_in, const int* in_sizes, int n_in,
                              void* d_out, int out_size, void* d_ws, size_t ws_size,
                              hipStream_t stream) {
    const float* P  = (const float*)d_in[0];
    const int*   wa = (const int*)d_in[1];
    const int*   wb = (const int*)d_in[2];
    float*       out = (float*)d_out;
    circuit_scan<<<NBATCH, 256, 0, stream>>>(P, wa, wb, out);
}